// Round 18
// baseline (4239.297 us; speedup 1.0000x reference)
//
#include <hip/hip_runtime.h>
#include <math.h>

#define DDIM 512
#define TLEN 128
#define RB   8
#define NWG  32
#define VDIM 32000
#define NWAVE 8
#define SR   528    // f16 units per srow/force row

typedef _Float16 f16x8 __attribute__((ext_vector_type(8)));
typedef float    f32x4 __attribute__((ext_vector_type(4)));
typedef _Float16 h2    __attribute__((ext_vector_type(2)));

__device__ __forceinline__ unsigned int pkh2(float a, float b) {
  h2 v; v.x = (_Float16)a; v.y = (_Float16)b;
  return __builtin_bit_cast(unsigned int, v);
}
__device__ __forceinline__ float h2f(unsigned short h) {
  return (float)__builtin_bit_cast(_Float16, h);
}
__device__ __forceinline__ unsigned short f2h(float f) {
  return __builtin_bit_cast(unsigned short, (_Float16)f);
}
__device__ __forceinline__ float tanh_fast(float x) {
#if __has_builtin(__builtin_amdgcn_exp2f) && __has_builtin(__builtin_amdgcn_rcpf)
  const float e = __builtin_amdgcn_exp2f(x * 2.885390081777927f);  // e^(2x)
  return 1.f - 2.f * __builtin_amdgcn_rcpf(e + 1.f);
#else
  const float e = exp2f(x * 2.885390081777927f);
  return 1.f - 2.f / (e + 1.f);
#endif
}
__device__ __forceinline__ f32x4 unpk4(uint2 u) {
  f32x4 r;
  r[0] = h2f((unsigned short)(u.x & 0xffff));
  r[1] = h2f((unsigned short)(u.x >> 16));
  r[2] = h2f((unsigned short)(u.y & 0xffff));
  r[3] = h2f((unsigned short)(u.y >> 16));
  return r;
}

// LDS-only barrier: does NOT drain vmcnt -> A-stream prefetch survives.
__device__ __forceinline__ void wg_barrier() {
  asm volatile("s_waitcnt lgkmcnt(0)" ::: "memory");
  __builtin_amdgcn_s_barrier();
  asm volatile("" ::: "memory");
}

// ---- pack diffusion into MFMA A-fragment order (validated) ------------------
// frag (it 0..31, kt 0..15), lane l, elem e: val = diff[it*16+(l&15)][kt*32+(l>>4)*8+e]
__global__ __launch_bounds__(256) void pack_diffusion(
    const float* __restrict__ A, uint4* __restrict__ pk)
{
  const int slot = blockIdx.x * 256 + threadIdx.x;   // 0..32767
  const int l  = slot & 63;
  const int fr = slot >> 6;
  const int kt = fr & 15;
  const int it = fr >> 4;
  const float* src = A + (size_t)(it * 16 + (l & 15)) * DDIM + kt * 32 + (l >> 4) * 8;
  pk[slot] = make_uint4(pkh2(src[0], src[1]), pkh2(src[2], src[3]),
                        pkh2(src[4], src[5]), pkh2(src[6], src[7]));
}

// ---- precompute LN scalars per (b,t): {mu, bi, b2} --------------------------
__global__ __launch_bounds__(512) void precompute_mubi(
    const int*   __restrict__ tokens,
    const float* __restrict__ embed,
    float4*      __restrict__ mubi)     // [256*128]
{
  const int idx = blockIdx.x * 8 + (threadIdx.x >> 6);
  const int l   = threadIdx.x & 63;
  const int b   = idx >> 7;
  const int t   = idx & 127;
  const int tok = tokens[b * TLEN + t];
  float s1 = 0.f, s2 = 0.f;
  #pragma unroll
  for (int e = 0; e < 8; ++e) {
    const float v = embed[(size_t)tok * DDIM + l + e * 64];
    s1 += v; s2 += v * v;
  }
  #pragma unroll
  for (int off = 32; off >= 1; off >>= 1) {
    s1 += __shfl_xor(s1, off);
    s2 += __shfl_xor(s2, off);
  }
  if (l == 0) {
    const float mu = s1 * (1.f / DDIM);
    float var = s2 * (1.f / DDIM) - mu * mu;
    var = fmaxf(var, 0.f);
    const float inv  = rsqrtf(var + 1e-5f);
    const float n2y  = (float)DDIM * var / (var + 1e-5f);
    const float invn = 1.f / fmaxf(sqrtf(n2y), 1e-12f);
    mubi[idx] = make_float4(mu, inv * invn, n2y * invn * invn, 0.f);
  }
}

// LDS-resident A (kt 0..3)
#define USE_LD(KT_)                                                          \
  {                                                                          \
    const f16x8 bf = *(const f16x8*)&srow[rp][rl * SR + (KT_) * 32 + g * 8]; \
    _Pragma("unroll")                                                        \
    for (int mt = 0; mt < 4; ++mt) {                                         \
      const uint4 af = ares[((w * 4 + mt) * 4 + (KT_)) * 64 + l];            \
      C[mt] = __builtin_amdgcn_mfma_f32_16x16x32_f16(                        \
          __builtin_bit_cast(f16x8, af), bf, C[mt], 0, 0, 0);                \
    }                                                                        \
  }
// streamed A (kt 4..15), 3-buffer rotation, cross-step wraparound refill
#define USE(B_, KT_)                                                         \
  {                                                                          \
    const f16x8 bf = *(const f16x8*)&srow[rp][rl * SR + (KT_) * 32 + g * 8]; \
    _Pragma("unroll")                                                        \
    for (int mt = 0; mt < 4; ++mt)                                           \
      C[mt] = __builtin_amdgcn_mfma_f32_16x16x32_f16(                        \
          __builtin_bit_cast(f16x8, B_[mt]), bf, C[mt], 0, 0, 0);            \
  }
#define PF(B_, KT_)                                                          \
  {                                                                          \
    _Pragma("unroll")                                                        \
    for (int mt = 0; mt < 4; ++mt)                                           \
      B_[mt] = apw[(size_t)(mt * 16 + (KT_)) * 64];                          \
  }

// ---- recurrence: 32 WGs x 512 thr; LDS 4kt resident, 12kt streamed ----------
__global__ __launch_bounds__(512, 1) void attractor_recurrence(
    const int*    __restrict__ tokens,
    const float*  __restrict__ embed,
    const uint4*  __restrict__ Apk,
    const float4* __restrict__ mubi,
    const float*  __restrict__ gamma_p,
    const float*  __restrict__ beta_p,
    float*        __restrict__ comb_out)   // [256][512]
{
  const int tid   = threadIdx.x;
  const int w     = tid >> 6;
  const int l     = tid & 63;
  const int g     = l >> 4;
  const int n     = l & 15;
  const int rl    = n & 7;
  const int hi    = (n >> 3) & 1;
  const int row0  = blockIdx.x * RB;
  const int wbase = w * 64;

  __shared__ unsigned short srow[2][RB * SR];   // raw state f16, double-buffered
  __shared__ unsigned short forceh[RB * SR];    // bss * sig, f16
  __shared__ float4 redc[2][NWAVE][RB];
  __shared__ float4 redt[NWAVE][2];
  __shared__ float2 carry[RB];
  __shared__ float4 mb[RB];
  __shared__ uint4  ares[32 * 4 * 64];          // LDS-resident A, kt 0..3 (128 KB)

  for (int x = tid; x < RB * SR; x += 512) { srow[0][x] = 0; srow[1][x] = 0; }
  for (int x = tid; x < 32 * 4 * 64; x += 512) {
    const int it = x >> 8;
    const int kr = (x >> 6) & 3;
    const int ll = x & 63;
    ares[x] = Apk[(size_t)(it * 16 + kr) * 64 + ll];
  }

  const uint4* apw = Apk + (size_t)(w * 64) * 64 + l;

  const float gamma = gamma_p[0];
  const float bss   = beta_p[0] * 0.5f;

  float fs[2][4];                 // RAW state, this lane's 2 M-tiles (hi-split)
  float sl[2][4];
  #pragma unroll
  for (int mtl = 0; mtl < 2; ++mtl)
    #pragma unroll
    for (int q = 0; q < 4; ++q) { fs[mtl][q] = 0.f; sl[mtl][q] = 0.f; }
  float S_reg = 0.f, S2_reg = 0.f, SX_reg = 0.f;
  float sl2 = 0.f;

  // prologue: embed gather for t=0
  float evc[8];
  #pragma unroll
  for (int r = 0; r < 8; ++r) {
    const int tok = tokens[(row0 + r) * TLEN + 0];
    evc[r] = embed[(size_t)tok * DDIM + tid];
  }

  __syncthreads();

  // initial stream prefetch (kt 4,5,6); addresses loop-invariant across steps
  uint4 A0[4], A1[4], A2[4];
  PF(A0, 4); PF(A1, 5); PF(A2, 6);

  for (int t = 0; t < TLEN; ++t) {
    //=========== alpha: gathers + state-dot partial + carry + slow update ====
    const int tn = (t + 1 < TLEN) ? t + 1 : t;
    float evn[8];
    #pragma unroll
    for (int r = 0; r < 8; ++r) {
      const int tok = tokens[(row0 + r) * TLEN + tn];
      evn[r] = embed[(size_t)tok * DDIM + tid];
    }
    if (tid < 8) mb[tid] = mubi[(size_t)(row0 + tid) * TLEN + t];
    float pr[8];
    #pragma unroll
    for (int r = 0; r < 8; ++r)
      pr[r] = evc[r] * h2f(srow[0][r * SR + tid]);   // ev . sp_raw
    #pragma unroll
    for (int off = 32; off >= 1; off >>= 1)
      #pragma unroll
      for (int q = 0; q < 8; ++q)
        pr[q] += __shfl_xor(pr[q], off);
    if (l == 0) {
      redt[w][0] = make_float4(pr[0], pr[1], pr[2], pr[3]);
      redt[w][1] = make_float4(pr[4], pr[5], pr[6], pr[7]);
    }
    if (tid < 8) carry[tid] = make_float2(S_reg, S2_reg);
    if (t > 0) {   // slow update for token t-1
      const float sq3   = sqrtf(S2_reg);
      const float ispn3 = 1.f / (sq3 + 1e-8f);
      const float fn3   = sq3 * ispn3;
      const float sdf   = SX_reg * ispn3;
      const float sn2   = 0.9025f * sl2 + 0.095f * sdf + 0.0025f * fn3 * fn3;
      const float sn    = sqrtf(fmaxf(sn2, 0.f));
      const float scale = (sn > 0.5f) ? 0.5f / (sn + 1e-12f) : 1.f;
      sl2 = sn2 * scale * scale;
      #pragma unroll
      for (int mtl = 0; mtl < 2; ++mtl)
        #pragma unroll
        for (int q = 0; q < 4; ++q)
          sl[mtl][q] = (0.95f * sl[mtl][q] + 0.05f * fs[mtl][q] * ispn3) * scale;
    }
    wg_barrier();   // B1

    //=========== beta: scalars per r + force (f16) ===========================
    {
      float rs[8];
      #pragma unroll
      for (int q = 0; q < 8; ++q) rs[q] = 0.f;
      #pragma unroll
      for (int wv = 0; wv < NWAVE; ++wv) {
        const float4 v0 = redt[wv][0];
        const float4 v1 = redt[wv][1];
        rs[0] += v0.x; rs[1] += v0.y; rs[2] += v0.z; rs[3] += v0.w;
        rs[4] += v1.x; rs[5] += v1.y; rs[6] += v1.z; rs[7] += v1.w;
      }
      #pragma unroll
      for (int r = 0; r < 8; ++r) {
        const float2 cy  = carry[r];
        const float4 mbr = mb[r];
        const float sq   = sqrtf(cy.y);
        const float ispr = 1.f / (sq + 1e-8f);
        const float fno  = sq * ispr;
        const float invf = 1.f / (fno + 1e-6f);
        const float qr   = ispr * invf;          // ctx = qr * sp_raw
        const float sctx = qr * cy.x;
        const float bdot = mbr.y * (qr * rs[r] - mbr.x * sctx);
        const float cn2  = qr * qr * cy.y;
        const float sg2  = mbr.z + 2.f * gamma * bdot + gamma * gamma * cn2;
        const float isig = 1.f / (sqrtf(fmaxf(sg2, 0.f)) + 1e-6f);
        const float ctx  = qr * h2f(srow[0][r * SR + tid]);
        forceh[r * SR + tid] = f2h(bss * ((evc[r] - mbr.x) * mbr.y + gamma * ctx) * isig);
      }
    }
    wg_barrier();   // B2

    //=========== conv steps: ONE lgkm-barrier each ===========================
    #pragma unroll 1
    for (int k = 0; k < 4; ++k) {
      const int  rp   = k & 1;
      const int  wp   = rp ^ 1;
      const bool last = (k == 3);

      f32x4 C[4];
      #pragma unroll
      for (int mt = 0; mt < 4; ++mt) C[mt] = (f32x4){0.f, 0.f, 0.f, 0.f};

      USE_LD(0); USE_LD(1); USE_LD(2); USE_LD(3);
      USE(A0,  4); PF(A0,  7);
      USE(A1,  5); PF(A1,  8);
      USE(A2,  6); PF(A2,  9);
      USE(A0,  7); PF(A0, 10);
      USE(A1,  8); PF(A1, 11);
      USE(A2,  9); PF(A2, 12);
      USE(A0, 10); PF(A0, 13);
      USE(A1, 11); PF(A1, 14);
      USE(A2, 12); PF(A2, 15);
      USE(A0, 13); PF(A0,  4);     // wraparound: refill for NEXT step
      USE(A1, 14); PF(A1,  5);
      USE(A2, 15); PF(A2,  6);

      // elementwise on this lane's 2 M-tiles (hi-split), scalar-folded norm
      const float ispn  = 1.f / (sqrtf(S2_reg) + 1e-8f);
      const float smean = S_reg * ispn * (1.f / DDIM);
      f32x4 Cs[2];
      Cs[0] = hi ? C[2] : C[0];
      Cs[1] = hi ? C[3] : C[1];
      const int i0base = wbase + hi * 32 + g * 4;
      float vs = 0.f, v2 = 0.f, vx = 0.f;
      #pragma unroll
      for (int mtl = 0; mtl < 2; ++mtl) {
        const int i0 = i0base + mtl * 16;
        const f32x4 ff = unpk4(*(const uint2*)&forceh[rl * SR + i0]);
        #pragma unroll
        for (int q = 0; q < 4; ++q) {
          const float s   = fs[mtl][q] * ispn;
          const float th  = tanh_fast(s - smean);
          const float dr  = Cs[mtl][q] * ispn + 0.008f * th + ff[q] - 0.1f * s;
          const float spv = fmaf(0.04f, dr, s);    // nan_to_num/clip no-ops
          fs[mtl][q] = spv;                         // raw for next step
          vs += spv; v2 += spv * spv;
          if (last) vx += sl[mtl][q] * spv;
        }
      }
      vs += __shfl_xor(vs, 8);  v2 += __shfl_xor(v2, 8);  vx += __shfl_xor(vx, 8);
      vs += __shfl_xor(vs, 16); v2 += __shfl_xor(v2, 16); vx += __shfl_xor(vx, 16);
      vs += __shfl_xor(vs, 32); v2 += __shfl_xor(v2, 32); vx += __shfl_xor(vx, 32);

      // publish raw state as f16 (every lane: its 2 tiles, lane-unique addr)
      #pragma unroll
      for (int mtl = 0; mtl < 2; ++mtl) {
        const int i0 = i0base + mtl * 16;
        uint2 pkv;
        pkv.x = pkh2(fs[mtl][0], fs[mtl][1]);
        pkv.y = pkh2(fs[mtl][2], fs[mtl][3]);
        *(uint2*)&srow[wp][rl * SR + i0] = pkv;
      }
      if (l < 8) redc[rp][w][l] = make_float4(vs, v2, vx, 0.f);
      wg_barrier();                // the ONLY barrier of this step (lgkm-only)
      float S = 0.f, S2 = 0.f, SX = 0.f;
      #pragma unroll
      for (int wv = 0; wv < NWAVE; ++wv) {
        const float4 v = redc[rp][wv][rl];
        S += v.x; S2 += v.y; SX += v.z;
      }
      S_reg = S; S2_reg = S2; SX_reg = SX;
    }

    #pragma unroll
    for (int r = 0; r < 8; ++r) evc[r] = evn[r];
  } // tokens

  //=========== epilogue: final slow update + comb write ======================
  {
    const float sq3   = sqrtf(S2_reg);
    const float ispn3 = 1.f / (sq3 + 1e-8f);
    const float fn3   = sq3 * ispn3;
    const float sdf   = SX_reg * ispn3;
    const float sn2   = 0.9025f * sl2 + 0.095f * sdf + 0.0025f * fn3 * fn3;
    const float sn    = sqrtf(fmaxf(sn2, 0.f));
    const float scale = (sn > 0.5f) ? 0.5f / (sn + 1e-12f) : 1.f;
    const int i0base = wbase + hi * 32 + g * 4;
    #pragma unroll
    for (int mtl = 0; mtl < 2; ++mtl) {
      const int i0 = i0base + mtl * 16;
      float4 o;
      #pragma unroll
      for (int q = 0; q < 4; ++q) {
        const float f = fs[mtl][q] * ispn3;
        const float s = (0.95f * sl[mtl][q] + 0.05f * f) * scale;
        ((float*)&o)[q] = f + 0.3f * s;
      }
      *(float4*)&comb_out[(size_t)(row0 + rl) * DDIM + i0] = o;
    }
  }
}

// ---- readout GEMM (unchanged) -----------------------------------------------
#define KC  32
#define LDT 132

__global__ __launch_bounds__(256) void logits_gemm(
    const float* __restrict__ comb,
    const float* __restrict__ W,
    float*       __restrict__ out)
{
  __shared__ float wt[KC * LDT];
  __shared__ float ct[KC * LDT];

  const int tid = threadIdx.x;
  const int v0  = blockIdx.x * 128;
  const int b0  = blockIdx.y * 128;
  const int tb  = tid >> 4;
  const int tv  = tid & 15;

  float acc[8][8];
  #pragma unroll
  for (int a = 0; a < 8; ++a)
    #pragma unroll
    for (int b = 0; b < 8; ++b) acc[a][b] = 0.f;

  for (int kk = 0; kk < DDIM; kk += KC) {
    #pragma unroll
    for (int it = 0; it < 4; ++it) {
      const int l4  = tid + it * 256;
      const int row = l4 >> 3;
      const int k4  = (l4 & 7) << 2;
      const float4 gw = *(const float4*)&W[(size_t)(v0 + row) * DDIM + kk + k4];
      const float4 gc = *(const float4*)&comb[(size_t)(b0 + row) * DDIM + kk + k4];
      wt[(k4 + 0) * LDT + row] = gw.x;
      wt[(k4 + 1) * LDT + row] = gw.y;
      wt[(k4 + 2) * LDT + row] = gw.z;
      wt[(k4 + 3) * LDT + row] = gw.w;
      ct[(k4 + 0) * LDT + row] = gc.x;
      ct[(k4 + 1) * LDT + row] = gc.y;
      ct[(k4 + 2) * LDT + row] = gc.z;
      ct[(k4 + 3) * LDT + row] = gc.w;
    }
    __syncthreads();

    for (int kx = 0; kx < KC; ++kx) {
      const float4 c0 = *(const float4*)&ct[kx * LDT + tb * 8];
      const float4 c1 = *(const float4*)&ct[kx * LDT + tb * 8 + 4];
      const float4 w0 = *(const float4*)&wt[kx * LDT + tv * 8];
      const float4 w1 = *(const float4*)&wt[kx * LDT + tv * 8 + 4];
      const float cw[8] = {c0.x, c0.y, c0.z, c0.w, c1.x, c1.y, c1.z, c1.w};
      const float wv[8] = {w0.x, w0.y, w0.z, w0.w, w1.x, w1.y, w1.z, w1.w};
      #pragma unroll
      for (int ib = 0; ib < 8; ++ib)
        #pragma unroll
        for (int iv = 0; iv < 8; ++iv)
          acc[ib][iv] = fmaf(cw[ib], wv[iv], acc[ib][iv]);
    }
    __syncthreads();
  }

  #pragma unroll
  for (int ib = 0; ib < 8; ++ib) {
    const size_t base = (size_t)(b0 + tb * 8 + ib) * VDIM + v0 + tv * 8;
    *(float4*)&out[base]     = make_float4(acc[ib][0], acc[ib][1], acc[ib][2], acc[ib][3]);
    *(float4*)&out[base + 4] = make_float4(acc[ib][4], acc[ib][5], acc[ib][6], acc[ib][7]);
  }
}

extern "C" void kernel_launch(void* const* d_in, const int* in_sizes, int n_in,
                              void* d_out, int out_size, void* d_ws, size_t ws_size,
                              hipStream_t stream) {
  const int*   tokens    = (const int*)d_in[0];
  const float* embed     = (const float*)d_in[1];
  const float* readout_w = (const float*)d_in[2];
  const float* diffusion = (const float*)d_in[3];
  const float* gamma_p   = (const float*)d_in[4];
  const float* beta_p    = (const float*)d_in[5];

  float*  comb = (float*)d_ws;                               // 512 KB
  uint4*  Apk  = (uint4*)((char*)d_ws + 512 * 1024);         // 512 KB
  float4* mubi = (float4*)((char*)d_ws + 1024 * 1024);       // 512 KB

  hipLaunchKernelGGL(pack_diffusion, dim3(128), dim3(256), 0, stream,
                     diffusion, Apk);
  hipLaunchKernelGGL(precompute_mubi, dim3(256 * TLEN / 8), dim3(512), 0, stream,
                     tokens, embed, mubi);
  hipLaunchKernelGGL(attractor_recurrence, dim3(NWG), dim3(512), 0, stream,
                     tokens, embed, Apk, mubi, gamma_p, beta_p, comb);
  hipLaunchKernelGGL(logits_gemm, dim3(VDIM / 128, 256 / 128), dim3(256), 0, stream,
                     comb, readout_w, (float*)d_out);
}

// Round 19
// 3253.775 us; speedup vs baseline: 1.3029x; 1.3029x over previous
//
#include <hip/hip_runtime.h>
#include <math.h>

#define DDIM 512
#define TLEN 128
#define RB   4
#define NWG  64
#define VDIM 32000
#define NWAVE 8
#define SR   528    // f16 units per srow/force row

typedef _Float16 f16x8 __attribute__((ext_vector_type(8)));
typedef float    f32x4 __attribute__((ext_vector_type(4)));
typedef _Float16 h2    __attribute__((ext_vector_type(2)));

__device__ __forceinline__ unsigned int pkh2(float a, float b) {
  h2 v; v.x = (_Float16)a; v.y = (_Float16)b;
  return __builtin_bit_cast(unsigned int, v);
}
__device__ __forceinline__ float h2f(unsigned short h) {
  return (float)__builtin_bit_cast(_Float16, h);
}
__device__ __forceinline__ unsigned short f2h(float f) {
  return __builtin_bit_cast(unsigned short, (_Float16)f);
}
__device__ __forceinline__ float tanh_fast(float x) {
#if __has_builtin(__builtin_amdgcn_exp2f) && __has_builtin(__builtin_amdgcn_rcpf)
  const float e = __builtin_amdgcn_exp2f(x * 2.885390081777927f);  // e^(2x)
  return 1.f - 2.f * __builtin_amdgcn_rcpf(e + 1.f);
#else
  const float e = exp2f(x * 2.885390081777927f);
  return 1.f - 2.f / (e + 1.f);
#endif
}
__device__ __forceinline__ f32x4 unpk4(uint2 u) {
  f32x4 r;
  r[0] = h2f((unsigned short)(u.x & 0xffff));
  r[1] = h2f((unsigned short)(u.x >> 16));
  r[2] = h2f((unsigned short)(u.y & 0xffff));
  r[3] = h2f((unsigned short)(u.y >> 16));
  return r;
}

// LDS-only barrier: does NOT drain vmcnt -> A-stream prefetch survives.
__device__ __forceinline__ void wg_barrier() {
  asm volatile("s_waitcnt lgkmcnt(0)" ::: "memory");
  __builtin_amdgcn_s_barrier();
  asm volatile("" ::: "memory");
}

// ---- pack diffusion into MFMA A-fragment order (validated) ------------------
// frag (it 0..31, kt 0..15), lane l, elem e: val = diff[it*16+(l&15)][kt*32+(l>>4)*8+e]
__global__ __launch_bounds__(256) void pack_diffusion(
    const float* __restrict__ A, uint4* __restrict__ pk)
{
  const int slot = blockIdx.x * 256 + threadIdx.x;   // 0..32767
  const int l  = slot & 63;
  const int fr = slot >> 6;
  const int kt = fr & 15;
  const int it = fr >> 4;
  const float* src = A + (size_t)(it * 16 + (l & 15)) * DDIM + kt * 32 + (l >> 4) * 8;
  pk[slot] = make_uint4(pkh2(src[0], src[1]), pkh2(src[2], src[3]),
                        pkh2(src[4], src[5]), pkh2(src[6], src[7]));
}

// ---- precompute LN scalars per (b,t): {mu, bi, b2} --------------------------
__global__ __launch_bounds__(512) void precompute_mubi(
    const int*   __restrict__ tokens,
    const float* __restrict__ embed,
    float4*      __restrict__ mubi)     // [256*128]
{
  const int idx = blockIdx.x * 8 + (threadIdx.x >> 6);
  const int l   = threadIdx.x & 63;
  const int b   = idx >> 7;
  const int t   = idx & 127;
  const int tok = tokens[b * TLEN + t];
  float s1 = 0.f, s2 = 0.f;
  #pragma unroll
  for (int e = 0; e < 8; ++e) {
    const float v = embed[(size_t)tok * DDIM + l + e * 64];
    s1 += v; s2 += v * v;
  }
  #pragma unroll
  for (int off = 32; off >= 1; off >>= 1) {
    s1 += __shfl_xor(s1, off);
    s2 += __shfl_xor(s2, off);
  }
  if (l == 0) {
    const float mu = s1 * (1.f / DDIM);
    float var = s2 * (1.f / DDIM) - mu * mu;
    var = fmaxf(var, 0.f);
    const float inv  = rsqrtf(var + 1e-5f);
    const float n2y  = (float)DDIM * var / (var + 1e-5f);
    const float invn = 1.f / fmaxf(sqrtf(n2y), 1e-12f);
    mubi[idx] = make_float4(mu, inv * invn, n2y * invn * invn, 0.f);
  }
}

// register-resident A (kt 0..3)
#define USE_AR(KT_)                                                          \
  {                                                                          \
    const f16x8 bf = *(const f16x8*)&srow[rp][rl * SR + (KT_) * 32 + g * 8]; \
    _Pragma("unroll")                                                        \
    for (int mt = 0; mt < 4; ++mt)                                           \
      C[mt] = __builtin_amdgcn_mfma_f32_16x16x32_f16(                        \
          __builtin_bit_cast(f16x8, AR[KT_][mt]), bf, C[mt], 0, 0, 0);       \
  }
// LDS-resident A (kt 4..7)
#define USE_LD(KT_)                                                          \
  {                                                                          \
    const f16x8 bf = *(const f16x8*)&srow[rp][rl * SR + (KT_) * 32 + g * 8]; \
    _Pragma("unroll")                                                        \
    for (int mt = 0; mt < 4; ++mt) {                                         \
      const uint4 af = ares[((w * 4 + mt) * 4 + ((KT_) - 4)) * 64 + l];      \
      C[mt] = __builtin_amdgcn_mfma_f32_16x16x32_f16(                        \
          __builtin_bit_cast(f16x8, af), bf, C[mt], 0, 0, 0);                \
    }                                                                        \
  }
// streamed A (kt 8..15), 3-buffer rotation, cross-step wraparound refill
#define USE(B_, KT_)                                                         \
  {                                                                          \
    const f16x8 bf = *(const f16x8*)&srow[rp][rl * SR + (KT_) * 32 + g * 8]; \
    _Pragma("unroll")                                                        \
    for (int mt = 0; mt < 4; ++mt)                                           \
      C[mt] = __builtin_amdgcn_mfma_f32_16x16x32_f16(                        \
          __builtin_bit_cast(f16x8, B_[mt]), bf, C[mt], 0, 0, 0);            \
  }
#define PF(B_, KT_)                                                          \
  {                                                                          \
    _Pragma("unroll")                                                        \
    for (int mt = 0; mt < 4; ++mt)                                           \
      B_[mt] = apw[(size_t)(mt * 16 + (KT_)) * 64];                          \
  }

// ---- recurrence: 64 WGs x 512 thr, 4 rows/WG; r14 residency/schedule --------
__global__ __launch_bounds__(512, 1) void attractor_recurrence(
    const int*    __restrict__ tokens,
    const float*  __restrict__ embed,
    const uint4*  __restrict__ Apk,
    const float4* __restrict__ mubi,
    const float*  __restrict__ gamma_p,
    const float*  __restrict__ beta_p,
    float*        __restrict__ comb_out)   // [256][512]
{
  const int tid   = threadIdx.x;
  const int w     = tid >> 6;
  const int l     = tid & 63;
  const int g     = l >> 4;
  const int n     = l & 15;
  const int rl    = n & 3;           // batch row (4-way dup in MFMA N)
  const int row0  = blockIdx.x * RB;
  const int wbase = w * 64;

  __shared__ unsigned short srow[2][RB * SR];   // raw state f16, double-buffered
  __shared__ unsigned short forceh[RB * SR];    // bss * sig, f16
  __shared__ float4 redc[2][NWAVE][RB];
  __shared__ float4 redt[NWAVE];                // 4-channel alpha partials
  __shared__ float2 carry[RB];
  __shared__ float4 mb[RB];
  __shared__ uint4  ares[32 * 4 * 64];          // LDS-resident A, kt 4..7 (128 KB)

  for (int x = tid; x < RB * SR; x += 512) { srow[0][x] = 0; srow[1][x] = 0; }
  for (int x = tid; x < 32 * 4 * 64; x += 512) {
    const int it = x >> 8;
    const int kr = (x >> 6) & 3;
    const int ll = x & 63;
    ares[x] = Apk[(size_t)(it * 16 + 4 + kr) * 64 + ll];
  }

  const uint4* apw = Apk + (size_t)(w * 64) * 64 + l;
  // register-resident A, kt 0..3 (64 regs/lane, loop-invariant, static idx)
  uint4 AR[4][4];
  #pragma unroll
  for (int kt = 0; kt < 4; ++kt)
    #pragma unroll
    for (int mt = 0; mt < 4; ++mt)
      AR[kt][mt] = apw[(size_t)(mt * 16 + kt) * 64];

  const float gamma = gamma_p[0];
  const float bss   = beta_p[0] * 0.5f;

  float fs[4], sl[4];             // RAW state / slow, lane's single M-tile
  #pragma unroll
  for (int q = 0; q < 4; ++q) { fs[q] = 0.f; sl[q] = 0.f; }
  float S_reg = 0.f, S2_reg = 0.f, SX_reg = 0.f;
  float sl2 = 0.f;

  // prologue: embed gather for t=0 (this thread's 4 rows at column tid)
  float evc[RB];
  #pragma unroll
  for (int r = 0; r < RB; ++r) {
    const int tok = tokens[(row0 + r) * TLEN + 0];
    evc[r] = embed[(size_t)tok * DDIM + tid];
  }

  __syncthreads();

  // initial stream prefetch (kt 8,9,10); addresses loop-invariant
  uint4 A0[4], A1[4], A2[4];
  PF(A0, 8); PF(A1, 9); PF(A2, 10);

  for (int t = 0; t < TLEN; ++t) {
    //=========== alpha: gathers + state-dot partial + carry + slow update ====
    const int tn = (t + 1 < TLEN) ? t + 1 : t;
    float evn[RB];
    #pragma unroll
    for (int r = 0; r < RB; ++r) {
      const int tok = tokens[(row0 + r) * TLEN + tn];
      evn[r] = embed[(size_t)tok * DDIM + tid];
    }
    if (tid < RB) mb[tid] = mubi[(size_t)(row0 + tid) * TLEN + t];
    float pr[RB];
    #pragma unroll
    for (int r = 0; r < RB; ++r)
      pr[r] = evc[r] * h2f(srow[0][r * SR + tid]);   // ev . sp_raw
    #pragma unroll
    for (int off = 32; off >= 1; off >>= 1)
      #pragma unroll
      for (int q = 0; q < RB; ++q)
        pr[q] += __shfl_xor(pr[q], off);
    if (l == 0)
      redt[w] = make_float4(pr[0], pr[1], pr[2], pr[3]);
    if (tid < RB) carry[tid] = make_float2(S_reg, S2_reg);
    if (t > 0) {   // slow update for token t-1 (register-resident)
      const float sq3   = sqrtf(S2_reg);
      const float ispn3 = 1.f / (sq3 + 1e-8f);
      const float fn3   = sq3 * ispn3;
      const float sdf   = SX_reg * ispn3;
      const float sn2   = 0.9025f * sl2 + 0.095f * sdf + 0.0025f * fn3 * fn3;
      const float sn    = sqrtf(fmaxf(sn2, 0.f));
      const float scale = (sn > 0.5f) ? 0.5f / (sn + 1e-12f) : 1.f;
      sl2 = sn2 * scale * scale;
      #pragma unroll
      for (int q = 0; q < 4; ++q)
        sl[q] = (0.95f * sl[q] + 0.05f * fs[q] * ispn3) * scale;
    }
    wg_barrier();   // B1

    //=========== beta: scalars per r + force (f16) ===========================
    {
      float rs[RB];
      #pragma unroll
      for (int q = 0; q < RB; ++q) rs[q] = 0.f;
      #pragma unroll
      for (int wv = 0; wv < NWAVE; ++wv) {
        const float4 v0 = redt[wv];
        rs[0] += v0.x; rs[1] += v0.y; rs[2] += v0.z; rs[3] += v0.w;
      }
      #pragma unroll
      for (int r = 0; r < RB; ++r) {
        const float2 cy  = carry[r];
        const float4 mbr = mb[r];
        const float sq   = sqrtf(cy.y);
        const float ispr = 1.f / (sq + 1e-8f);
        const float fno  = sq * ispr;
        const float invf = 1.f / (fno + 1e-6f);
        const float qr   = ispr * invf;          // ctx = qr * sp_raw
        const float sctx = qr * cy.x;
        const float bdot = mbr.y * (qr * rs[r] - mbr.x * sctx);
        const float cn2  = qr * qr * cy.y;
        const float sg2  = mbr.z + 2.f * gamma * bdot + gamma * gamma * cn2;
        const float isig = 1.f / (sqrtf(fmaxf(sg2, 0.f)) + 1e-6f);
        const float ctx  = qr * h2f(srow[0][r * SR + tid]);
        forceh[r * SR + tid] = f2h(bss * ((evc[r] - mbr.x) * mbr.y + gamma * ctx) * isig);
      }
    }
    wg_barrier();   // B2

    //=========== conv steps: ONE lgkm-barrier each ===========================
    #pragma unroll 1
    for (int k = 0; k < 4; ++k) {
      const int  rp   = k & 1;
      const int  wp   = rp ^ 1;
      const bool last = (k == 3);

      f32x4 C[4];
      #pragma unroll
      for (int mt = 0; mt < 4; ++mt) C[mt] = (f32x4){0.f, 0.f, 0.f, 0.f};

      USE_AR(0); USE_AR(1); USE_AR(2); USE_AR(3);
      USE_LD(4); USE_LD(5); USE_LD(6); USE_LD(7);
      USE(A0,  8); PF(A0, 11);
      USE(A1,  9); PF(A1, 12);
      USE(A2, 10); PF(A2, 13);
      USE(A0, 11); PF(A0, 14);
      USE(A1, 12); PF(A1, 15);
      USE(A2, 13); PF(A2, 10);     // wraparound: refill for NEXT step
      USE(A0, 14); PF(A0,  8);
      USE(A1, 15); PF(A1,  9);

      // elementwise on lane's single M-tile (mtl = n>>2), static select
      const float ispn  = 1.f / (sqrtf(S2_reg) + 1e-8f);
      const float smean = S_reg * ispn * (1.f / DDIM);
      const int b2 = (n >> 3) & 1, b1 = (n >> 2) & 1;
      const f32x4 Cs = b2 ? (b1 ? C[3] : C[2]) : (b1 ? C[1] : C[0]);
      const int i0 = wbase + ((n >> 2) << 4) + g * 4;
      const f32x4 ff = unpk4(*(const uint2*)&forceh[rl * SR + i0]);
      float vs = 0.f, v2 = 0.f, vx = 0.f;
      #pragma unroll
      for (int q = 0; q < 4; ++q) {
        const float s   = fs[q] * ispn;
        const float th  = tanh_fast(s - smean);
        const float dr  = Cs[q] * ispn + 0.008f * th + ff[q] - 0.1f * s;
        const float spv = fmaf(0.04f, dr, s);    // nan_to_num/clip no-ops
        fs[q] = spv;                              // raw for next step
        vs += spv; v2 += spv * spv;
        if (last) vx += sl[q] * spv;
      }
      vs += __shfl_xor(vs, 4);  v2 += __shfl_xor(v2, 4);  vx += __shfl_xor(vx, 4);
      vs += __shfl_xor(vs, 8);  v2 += __shfl_xor(v2, 8);  vx += __shfl_xor(vx, 8);
      vs += __shfl_xor(vs, 16); v2 += __shfl_xor(v2, 16); vx += __shfl_xor(vx, 16);
      vs += __shfl_xor(vs, 32); v2 += __shfl_xor(v2, 32); vx += __shfl_xor(vx, 32);

      {   // publish raw state as f16 (lane-unique (rl, mtl, g) address)
        uint2 pkv;
        pkv.x = pkh2(fs[0], fs[1]);
        pkv.y = pkh2(fs[2], fs[3]);
        *(uint2*)&srow[wp][rl * SR + i0] = pkv;
      }
      if (l < RB) redc[rp][w][l] = make_float4(vs, v2, vx, 0.f);
      wg_barrier();                // the ONLY barrier of this step (lgkm-only)
      float S = 0.f, S2 = 0.f, SX = 0.f;
      #pragma unroll
      for (int wv = 0; wv < NWAVE; ++wv) {
        const float4 v = redc[rp][wv][rl];
        S += v.x; S2 += v.y; SX += v.z;
      }
      S_reg = S; S2_reg = S2; SX_reg = SX;   // each element counted once
    }

    #pragma unroll
    for (int r = 0; r < RB; ++r) evc[r] = evn[r];
  } // tokens

  //=========== epilogue: final slow update + comb write ======================
  {
    const float sq3   = sqrtf(S2_reg);
    const float ispn3 = 1.f / (sq3 + 1e-8f);
    const float fn3   = sq3 * ispn3;
    const float sdf   = SX_reg * ispn3;
    const float sn2   = 0.9025f * sl2 + 0.095f * sdf + 0.0025f * fn3 * fn3;
    const float sn    = sqrtf(fmaxf(sn2, 0.f));
    const float scale = (sn > 0.5f) ? 0.5f / (sn + 1e-12f) : 1.f;
    const int i0 = wbase + ((n >> 2) << 4) + g * 4;
    float4 o;
    #pragma unroll
    for (int q = 0; q < 4; ++q) {
      const float f = fs[q] * ispn3;
      const float s = (0.95f * sl[q] + 0.05f * f) * scale;
      ((float*)&o)[q] = f + 0.3f * s;
    }
    *(float4*)&comb_out[(size_t)(row0 + rl) * DDIM + i0] = o;
  }
}

// ---- readout GEMM (unchanged) -----------------------------------------------
#define KC  32
#define LDT 132

__global__ __launch_bounds__(256) void logits_gemm(
    const float* __restrict__ comb,
    const float* __restrict__ W,
    float*       __restrict__ out)
{
  __shared__ float wt[KC * LDT];
  __shared__ float ct[KC * LDT];

  const int tid = threadIdx.x;
  const int v0  = blockIdx.x * 128;
  const int b0  = blockIdx.y * 128;
  const int tb  = tid >> 4;
  const int tv  = tid & 15;

  float acc[8][8];
  #pragma unroll
  for (int a = 0; a < 8; ++a)
    #pragma unroll
    for (int b = 0; b < 8; ++b) acc[a][b] = 0.f;

  for (int kk = 0; kk < DDIM; kk += KC) {
    #pragma unroll
    for (int it = 0; it < 4; ++it) {
      const int l4  = tid + it * 256;
      const int row = l4 >> 3;
      const int k4  = (l4 & 7) << 2;
      const float4 gw = *(const float4*)&W[(size_t)(v0 + row) * DDIM + kk + k4];
      const float4 gc = *(const float4*)&comb[(size_t)(b0 + row) * DDIM + kk + k4];
      wt[(k4 + 0) * LDT + row] = gw.x;
      wt[(k4 + 1) * LDT + row] = gw.y;
      wt[(k4 + 2) * LDT + row] = gw.z;
      wt[(k4 + 3) * LDT + row] = gw.w;
      ct[(k4 + 0) * LDT + row] = gc.x;
      ct[(k4 + 1) * LDT + row] = gc.y;
      ct[(k4 + 2) * LDT + row] = gc.z;
      ct[(k4 + 3) * LDT + row] = gc.w;
    }
    __syncthreads();

    for (int kx = 0; kx < KC; ++kx) {
      const float4 c0 = *(const float4*)&ct[kx * LDT + tb * 8];
      const float4 c1 = *(const float4*)&ct[kx * LDT + tb * 8 + 4];
      const float4 w0 = *(const float4*)&wt[kx * LDT + tv * 8];
      const float4 w1 = *(const float4*)&wt[kx * LDT + tv * 8 + 4];
      const float cw[8] = {c0.x, c0.y, c0.z, c0.w, c1.x, c1.y, c1.z, c1.w};
      const float wv[8] = {w0.x, w0.y, w0.z, w0.w, w1.x, w1.y, w1.z, w1.w};
      #pragma unroll
      for (int ib = 0; ib < 8; ++ib)
        #pragma unroll
        for (int iv = 0; iv < 8; ++iv)
          acc[ib][iv] = fmaf(cw[ib], wv[iv], acc[ib][iv]);
    }
    __syncthreads();
  }

  #pragma unroll
  for (int ib = 0; ib < 8; ++ib) {
    const size_t base = (size_t)(b0 + tb * 8 + ib) * VDIM + v0 + tv * 8;
    *(float4*)&out[base]     = make_float4(acc[ib][0], acc[ib][1], acc[ib][2], acc[ib][3]);
    *(float4*)&out[base + 4] = make_float4(acc[ib][4], acc[ib][5], acc[ib][6], acc[ib][7]);
  }
}

extern "C" void kernel_launch(void* const* d_in, const int* in_sizes, int n_in,
                              void* d_out, int out_size, void* d_ws, size_t ws_size,
                              hipStream_t stream) {
  const int*   tokens    = (const int*)d_in[0];
  const float* embed     = (const float*)d_in[1];
  const float* readout_w = (const float*)d_in[2];
  const float* diffusion = (const float*)d_in[3];
  const float* gamma_p   = (const float*)d_in[4];
  const float* beta_p    = (const float*)d_in[5];

  float*  comb = (float*)d_ws;                               // 512 KB
  uint4*  Apk  = (uint4*)((char*)d_ws + 512 * 1024);         // 512 KB
  float4* mubi = (float4*)((char*)d_ws + 1024 * 1024);       // 512 KB

  hipLaunchKernelGGL(pack_diffusion, dim3(128), dim3(256), 0, stream,
                     diffusion, Apk);
  hipLaunchKernelGGL(precompute_mubi, dim3(256 * TLEN / 8), dim3(512), 0, stream,
                     tokens, embed, mubi);
  hipLaunchKernelGGL(attractor_recurrence, dim3(NWG), dim3(512), 0, stream,
                     tokens, embed, Apk, mubi, gamma_p, beta_p, comb);
  hipLaunchKernelGGL(logits_gemm, dim3(VDIM / 128, 256 / 128), dim3(256), 0, stream,
                     comb, readout_w, (float*)d_out);
}